// Round 14
// baseline (1095.841 us; speedup 1.0000x reference)
//
#include <hip/hip_runtime.h>

typedef unsigned short u16;
typedef __attribute__((ext_vector_type(8))) short short8;
typedef __attribute__((ext_vector_type(4))) float float4v;

#define B_   16
#define L_   495
#define D_   384
#define DI_  768
#define DS_  16
#define DTR_ 24
#define M_   (B_ * L_)
#define NBD  (B_ * 12)            // 192 (b,d-block) pairs
#define LOG2E 1.44269504f
#define CNCH 15
#define CTL  34

__device__ __forceinline__ float bf2f(u16 u) {
    return __uint_as_float(((unsigned)u) << 16);
}
__device__ __forceinline__ u16 f2bf(float f) {
    unsigned u = __float_as_uint(f);
    unsigned r = 0x7fffu + ((u >> 16) & 1u);
    return (u16)((u + r) >> 16);
}
__device__ __forceinline__ float silu_f(float x) {
    return x / (1.f + __expf(-x));
}

// ---- dtype detector (parallel): A_log in [0,2.78] as bf16 => bad==0 -> bf16.
__global__ __launch_bounds__(256) void detect_kernel(
    const u16* __restrict__ alog_raw, int* __restrict__ bad)
{
    int i = blockIdx.x * 256 + threadIdx.x;
    float v = bf2f(alog_raw[i]);
    int b = !(v >= -1e-3f && v <= 2.8f);
    unsigned long long m = __ballot(b);
    if ((threadIdx.x & 63) == 0 && m) atomicAdd(bad, (int)__popcll(m));
}

// ---- batched convert (blockIdx.y = tensor). tobf: emit bf16 instead of f32.
struct CvtArgs {
    const void* src[11];
    void* dst[11];
    int n[11];
    int tobf[11];
};
__global__ __launch_bounds__(256) void cvt_all_kernel(CvtArgs a, const int* __restrict__ bad)
{
    int t = blockIdx.y;
    int i = blockIdx.x * 256 + threadIdx.x;
    if (i >= a.n[t]) return;
    int isbf = (*bad == 0);
    if (a.tobf[t]) {
        u16 v = isbf ? ((const u16*)a.src[t])[i] : f2bf(((const float*)a.src[t])[i]);
        ((u16*)a.dst[t])[i] = v;
    } else {
        float v = isbf ? bf2f(((const u16*)a.src[t])[i]) : ((const float*)a.src[t])[i];
        ((float*)a.dst[t])[i] = v;
    }
}

// hidden[b,l,c] = concat(cjv[:247], cls, cjv[247:]) + pos_embed  (raw inputs)
__global__ __launch_bounds__(256) void build_hidden_kernel(
    const void* __restrict__ cjv, const void* __restrict__ cls,
    const void* __restrict__ pos, float* __restrict__ hidden,
    const int* __restrict__ bad)
{
    int isbf = (*bad == 0);
    int i = blockIdx.x * 256 + threadIdx.x;
    int c = i % D_;
    int l = (i / D_) % L_;
    int b = i / (D_ * L_);
    size_t si;
    const void* sp;
    if (l < 247)       { sp = cjv; si = ((size_t)b * 494 + l) * D_ + c; }
    else if (l == 247) { sp = cls; si = c; }
    else               { sp = cjv; si = ((size_t)b * 494 + (l - 1)) * D_ + c; }
    float v = isbf ? bf2f(((const u16*)sp)[si]) : ((const float*)sp)[si];
    size_t pi = (size_t)l * D_ + c;
    float p = isbf ? bf2f(((const u16*)pos)[pi]) : ((const float*)pos)[pi];
    hidden[i] = v + p;
}

// resid = hidden (+ resid); hbf <- bf16(rmsnorm(resid)*w)
__global__ __launch_bounds__(128) void resnorm_kernel(
    const float* __restrict__ hidden, float* __restrict__ resid,
    const float* __restrict__ w, u16* __restrict__ hbf, int first)
{
    int m = blockIdx.x, tid = threadIdx.x;
    size_t base = (size_t)m * D_;
    float v[3]; float ss = 0.f;
#pragma unroll
    for (int i = 0; i < 3; ++i) {
        int c = tid + i * 128;
        float r = hidden[base + c];
        if (!first) r += resid[base + c];
        resid[base + c] = r;
        v[i] = r; ss += r * r;
    }
    ss += __shfl_xor(ss, 32); ss += __shfl_xor(ss, 16); ss += __shfl_xor(ss, 8);
    ss += __shfl_xor(ss, 4);  ss += __shfl_xor(ss, 2);  ss += __shfl_xor(ss, 1);
    __shared__ float sred[2];
    if ((tid & 63) == 0) sred[tid >> 6] = ss;
    __syncthreads();
    float scale = rsqrtf((sred[0] + sred[1]) * (1.f / D_) + 1e-5f);
#pragma unroll
    for (int i = 0; i < 3; ++i) {
        int c = tid + i * 128;
        hbf[base + c] = f2bf(v[i] * scale * w[c]);
    }
}

// ===== MFMA GEMM: C = alpha * (A [+ A2][*silu(z)])(M,K)bf16 @ W(N,K)bf16^T =====
// ZGATE (with SUM2): A-staging computes (a0+a1)*silu(z), z at Z[m*1536+768+k].
template<int CF32, int SUM2, int ZGATE>
__global__ __launch_bounds__(256) void gemm_mfma_bt(
    const u16* __restrict__ A, const u16* __restrict__ A2,
    const u16* __restrict__ Z,
    const u16* __restrict__ W, void* __restrict__ Cv,
    int M, int N, int K, int ldc, float alpha)
{
    __shared__ __align__(16) u16 As[128 * 40];
    __shared__ __align__(16) u16 Ws[128 * 40];
    int tid = threadIdx.x;
    int wave = tid >> 6, lane = tid & 63;
    int m0 = blockIdx.x * 128, n0 = blockIdx.y * 128;
    int wm = (wave >> 1) * 64, wn = (wave & 1) * 64;
    int ml = lane & 15, quad = lane >> 4;

    float4v acc[4][4];
#pragma unroll
    for (int i = 0; i < 4; ++i)
#pragma unroll
        for (int j = 0; j < 4; ++j)
#pragma unroll
            for (int r = 0; r < 4; ++r) acc[i][j][r] = 0.f;

    int srow = tid >> 2;
    int scol = (tid & 3) * 8;

    for (int k0 = 0; k0 < K; k0 += 32) {
#pragma unroll
        for (int p = 0; p < 2; ++p) {
            int row = srow + p * 64;
            int gm = m0 + row; if (gm >= M) gm = M - 1;
            if (SUM2) {
                short8 a0 = *(const short8*)(A  + (size_t)gm * K + k0 + scol);
                short8 a1 = *(const short8*)(A2 + (size_t)gm * K + k0 + scol);
                short8 z8;
                if (ZGATE) z8 = *(const short8*)(Z + (size_t)gm * 1536 + 768 + k0 + scol);
                u16 tmp[8];
#pragma unroll
                for (int r = 0; r < 8; ++r) {
                    float v = bf2f((u16)a0[r]) + bf2f((u16)a1[r]);
                    if (ZGATE) v *= silu_f(bf2f((u16)z8[r]));
                    tmp[r] = f2bf(v);
                }
                *(uint4*)&As[row * 40 + scol] = *(const uint4*)tmp;
            } else {
                *(uint4*)&As[row * 40 + scol] =
                    *(const uint4*)(A + (size_t)gm * K + k0 + scol);
            }
            int gn = n0 + row;
            *(uint4*)&Ws[row * 40 + scol] =
                *(const uint4*)(W + (size_t)gn * K + k0 + scol);
        }
        __syncthreads();
        short8 af[4], bfr[4];
#pragma unroll
        for (int i = 0; i < 4; ++i) {
            af[i]  = *(const short8*)&As[(wm + i * 16 + ml) * 40 + quad * 8];
            bfr[i] = *(const short8*)&Ws[(wn + i * 16 + ml) * 40 + quad * 8];
        }
#pragma unroll
        for (int i = 0; i < 4; ++i)
#pragma unroll
            for (int j = 0; j < 4; ++j)
                acc[i][j] = __builtin_amdgcn_mfma_f32_16x16x32_bf16(
                    af[i], bfr[j], acc[i][j], 0, 0, 0);
        __syncthreads();
    }

#pragma unroll
    for (int i = 0; i < 4; ++i)
#pragma unroll
        for (int j = 0; j < 4; ++j)
#pragma unroll
            for (int r = 0; r < 4; ++r) {
                int m = m0 + wm + i * 16 + quad * 4 + r;
                if (m >= M) continue;
                int n = n0 + wn + j * 16 + ml;
                float val = alpha * acc[i][j][r];
                if (CF32) ((float*)Cv)[(size_t)m * ldc + n] = val;
                else      ((u16*)Cv)[(size_t)m * ldc + n] = f2bf(val);
            }
}

// ===== xproj MFMA GEMM: dbl2[dir](m,56) = xc2[dir](M,768) @ xpWb[dir](56,768)^T
__global__ __launch_bounds__(256) void xproj_gemm_kernel(
    const u16* __restrict__ xc2, const u16* __restrict__ xpWb_l,
    float* __restrict__ dbl2)
{
    int dir = blockIdx.y;
    const u16* A = xc2 + (size_t)dir * M_ * DI_;
    const u16* W = xpWb_l + (size_t)dir * 56 * DI_;
    float* C = dbl2 + (size_t)dir * M_ * 56;

    __shared__ __align__(16) u16 As[128 * 40];
    __shared__ __align__(16) u16 Ws[64 * 40];
    int tid = threadIdx.x;
    int wave = tid >> 6, lane = tid & 63;
    int m0 = blockIdx.x * 128;
    int wm = wave * 32;
    int ml = lane & 15, quad = lane >> 4;

    float4v acc[2][4];
#pragma unroll
    for (int i = 0; i < 2; ++i)
#pragma unroll
        for (int j = 0; j < 4; ++j)
#pragma unroll
            for (int r = 0; r < 4; ++r) acc[i][j][r] = 0.f;

    int srow = tid >> 2;
    int scol = (tid & 3) * 8;

    for (int k0 = 0; k0 < DI_; k0 += 32) {
#pragma unroll
        for (int p = 0; p < 2; ++p) {
            int row = srow + p * 64;
            int gm = m0 + row; if (gm >= M_) gm = M_ - 1;
            *(uint4*)&As[row * 40 + scol] =
                *(const uint4*)(A + (size_t)gm * DI_ + k0 + scol);
        }
        *(uint4*)&Ws[srow * 40 + scol] =
            *(const uint4*)(W + (size_t)srow * DI_ + k0 + scol);
        __syncthreads();
        short8 af[2], bfr[4];
#pragma unroll
        for (int i = 0; i < 2; ++i)
            af[i] = *(const short8*)&As[(wm + i * 16 + ml) * 40 + quad * 8];
#pragma unroll
        for (int j = 0; j < 4; ++j)
            bfr[j] = *(const short8*)&Ws[(j * 16 + ml) * 40 + quad * 8];
#pragma unroll
        for (int i = 0; i < 2; ++i)
#pragma unroll
            for (int j = 0; j < 4; ++j)
                acc[i][j] = __builtin_amdgcn_mfma_f32_16x16x32_bf16(
                    af[i], bfr[j], acc[i][j], 0, 0, 0);
        __syncthreads();
    }

#pragma unroll
    for (int i = 0; i < 2; ++i)
#pragma unroll
        for (int j = 0; j < 4; ++j)
#pragma unroll
            for (int r = 0; r < 4; ++r) {
                int m = m0 + wm + i * 16 + quad * 4 + r;
                int n = j * 16 + ml;
                if (m < M_ && n < 56)
                    C[(size_t)m * 56 + n] = acc[i][j][r];
            }
}

// ===== dtproj MFMA GEMM: delta2[dir](M,768) = softplus(dt(M,24)@dtW(768,24)^T + dtb)
__global__ __launch_bounds__(256) void dtproj_gemm_kernel(
    const float* __restrict__ dbl2, const float* __restrict__ dtW_l,
    const float* __restrict__ dtb_l, u16* __restrict__ delta2)
{
    int dir = blockIdx.z;
    const float* dbl = dbl2 + (size_t)dir * M_ * 56;
    const float* dtW = dtW_l + (size_t)dir * DI_ * DTR_;
    const float* dtb = dtb_l + (size_t)dir * DI_;
    u16* dout = delta2 + (size_t)dir * M_ * DI_;

    __shared__ __align__(16) u16 As[128 * 40];
    __shared__ __align__(16) u16 Ws[128 * 40];
    int tid = threadIdx.x;
    int wave = tid >> 6, lane = tid & 63;
    int m0 = blockIdx.x * 128, n0 = blockIdx.y * 128;
    int wm = (wave >> 1) * 64, wn = (wave & 1) * 64;
    int ml = lane & 15, quad = lane >> 4;

    {
        int r = tid >> 1, hh = tid & 1;
        int gm = m0 + r; if (gm >= M_) gm = M_ - 1;
        const float* srcA = dbl + (size_t)gm * 56 + hh * 12;
        const float* srcW = dtW + (size_t)(n0 + r) * DTR_ + hh * 12;
#pragma unroll
        for (int i = 0; i < 6; ++i) {
            unsigned a = (unsigned)f2bf(srcA[2 * i]) | ((unsigned)f2bf(srcA[2 * i + 1]) << 16);
            unsigned w = (unsigned)f2bf(srcW[2 * i]) | ((unsigned)f2bf(srcW[2 * i + 1]) << 16);
            *(unsigned*)&As[r * 40 + hh * 12 + 2 * i] = a;
            *(unsigned*)&Ws[r * 40 + hh * 12 + 2 * i] = w;
        }
        if (hh) {
            *(uint4*)&As[r * 40 + 24] = make_uint4(0, 0, 0, 0);
            *(uint4*)&Ws[r * 40 + 24] = make_uint4(0, 0, 0, 0);
        }
    }
    __syncthreads();

    float4v acc[4][4];
#pragma unroll
    for (int i = 0; i < 4; ++i)
#pragma unroll
        for (int j = 0; j < 4; ++j)
#pragma unroll
            for (int r = 0; r < 4; ++r) acc[i][j][r] = 0.f;

    short8 af[4], bfr[4];
#pragma unroll
    for (int i = 0; i < 4; ++i) {
        af[i]  = *(const short8*)&As[(wm + i * 16 + ml) * 40 + quad * 8];
        bfr[i] = *(const short8*)&Ws[(wn + i * 16 + ml) * 40 + quad * 8];
    }
#pragma unroll
    for (int i = 0; i < 4; ++i)
#pragma unroll
        for (int j = 0; j < 4; ++j)
            acc[i][j] = __builtin_amdgcn_mfma_f32_16x16x32_bf16(
                af[i], bfr[j], acc[i][j], 0, 0, 0);

#pragma unroll
    for (int i = 0; i < 4; ++i)
#pragma unroll
        for (int j = 0; j < 4; ++j) {
            int n = n0 + wn + j * 16 + ml;
            float bv = dtb[n];
#pragma unroll
            for (int r = 0; r < 4; ++r) {
                int m = m0 + wm + i * 16 + quad * 4 + r;
                if (m >= M_) continue;
                float s = acc[i][j][r] + bv;
                float dl = (s > 20.f) ? s : __logf(1.f + __expf(s));
                dout[(size_t)m * DI_ + n] = f2bf(dl);
            }
        }
}

// ===== fused dual-direction causal depthwise conv (K=4) + bias + silu =====
__global__ __launch_bounds__(384) void conv_fused_kernel(
    const u16* __restrict__ xz, const float* __restrict__ cw_l,
    const float* __restrict__ cb_l, u16* __restrict__ xc2)
{
    int dp = threadIdx.x;
    int d = dp * 2;
    int blk = blockIdx.x;
    int b = blk / CNCH, c = blk % CNCH;
    int t0 = c * CTL;
    int t1 = t0 + CTL; if (t1 > L_ + 3) t1 = L_ + 3;
    size_t mb = (size_t)b * L_;
    u16* xc0 = xc2;
    u16* xc1 = xc2 + (size_t)M_ * DI_;

    float w0[2][4], w1[2][4];
    {
        float4 a = *(const float4*)&cw_l[d * 4];
        float4 bq = *(const float4*)&cw_l[d * 4 + 4];
        w0[0][0] = a.x; w0[0][1] = a.y; w0[0][2] = a.z; w0[0][3] = a.w;
        w0[1][0] = bq.x; w0[1][1] = bq.y; w0[1][2] = bq.z; w0[1][3] = bq.w;
        float4 e = *(const float4*)&cw_l[DI_ * 4 + d * 4];
        float4 f = *(const float4*)&cw_l[DI_ * 4 + d * 4 + 4];
        w1[0][0] = e.x; w1[0][1] = e.y; w1[0][2] = e.z; w1[0][3] = e.w;
        w1[1][0] = f.x; w1[1][1] = f.y; w1[1][2] = f.z; w1[1][3] = f.w;
    }
    float b00 = cb_l[d], b01 = cb_l[d + 1];
    float b10 = cb_l[DI_ + d], b11 = cb_l[DI_ + d + 1];

    unsigned win[4];
#pragma unroll
    for (int m = 0; m < 3; ++m) {
        int r = t0 - 3 + m;
        win[m] = (r >= 0 && r < L_) ?
            *(const unsigned*)&xz[(mb + r) * 1536 + d] : 0u;
    }

    for (int t = t0; t < t1; ++t) {
        win[3] = (t < L_) ? *(const unsigned*)&xz[(mb + t) * 1536 + d] : 0u;
        float x0[4], x1[4];
#pragma unroll
        for (int m = 0; m < 4; ++m) {
            x0[m] = __uint_as_float(win[m] << 16);
            x1[m] = __uint_as_float(win[m] & 0xffff0000u);
        }
        if (t < L_) {
            float a0 = b00 + w0[0][0] * x0[0] + w0[0][1] * x0[1]
                           + w0[0][2] * x0[2] + w0[0][3] * x0[3];
            float a1 = b01 + w0[1][0] * x1[0] + w0[1][1] * x1[1]
                           + w0[1][2] * x1[2] + w0[1][3] * x1[3];
            unsigned o = (unsigned)f2bf(silu_f(a0)) | ((unsigned)f2bf(silu_f(a1)) << 16);
            *(unsigned*)&xc0[(mb + t) * DI_ + d] = o;
        }
        if (t >= 3) {
            int s1 = L_ + 2 - t;
            float a0 = b10 + w1[0][3] * x0[0] + w1[0][2] * x0[1]
                           + w1[0][1] * x0[2] + w1[0][0] * x0[3];
            float a1 = b11 + w1[1][3] * x1[0] + w1[1][2] * x1[1]
                           + w1[1][1] * x1[2] + w1[1][0] * x1[3];
            unsigned o = (unsigned)f2bf(silu_f(a0)) | ((unsigned)f2bf(silu_f(a1)) << 16);
            *(unsigned*)&xc1[(mb + s1) * DI_ + d] = o;
        }
        win[0] = win[1]; win[1] = win[2]; win[2] = win[3];
    }
}

// ================= segmented selective scan, templated on SEG ==========
// Part 1: local scan; delta precomputed; P algebraic via sum(dl); prefetch t+1.
template<int SEGT>
__global__ __launch_bounds__(256) void scan_part1_kernel(
    const u16* __restrict__ xc2, const float* __restrict__ dbl2,
    const u16* __restrict__ delta2, const float* __restrict__ Alog_l,
    u16* __restrict__ P_buf, u16* __restrict__ q_buf)
{
    const int TLT = (L_ + SEGT - 1) / SEGT;
    const int SGRIDT = NBD * SEGT;
    int dir = blockIdx.y;
    const u16* xc = xc2 + (size_t)dir * M_ * DI_;
    const float* dbl = dbl2 + (size_t)dir * M_ * 56;
    const u16* din = delta2 + (size_t)dir * M_ * DI_;
    const float* Alog = Alog_l + (size_t)dir * DI_ * DS_;

    int tid = threadIdx.x;
    int wave = tid >> 6, lane = tid & 63;
    int s = blockIdx.x % SEGT;
    int bq = blockIdx.x / SEGT;
    int b = bq / 3, dq = bq % 3;
    int dblk = dq * 4 + wave;
    int d = dblk * 64 + lane;
    size_t mb = (size_t)b * L_;
    int t0 = s * TLT;
    int t1 = (t0 + TLT < L_) ? (t0 + TLT) : L_;

    float A[16];
    {
        const float4* ap = reinterpret_cast<const float4*>(Alog + (size_t)d * 16);
#pragma unroll
        for (int i = 0; i < 4; ++i) {
            float4 a4 = ap[i];
            A[4 * i + 0] = -LOG2E * __expf(a4.x); A[4 * i + 1] = -LOG2E * __expf(a4.y);
            A[4 * i + 2] = -LOG2E * __expf(a4.z); A[4 * i + 3] = -LOG2E * __expf(a4.w);
        }
    }
    float h[16];
    float S = 0.f;
#pragma unroll
    for (int i = 0; i < 16; ++i) h[i] = 0.f;

    float dl = 0.f, xv = 0.f;
    if (t0 < t1) {
        dl = bf2f(din[(mb + t0) * DI_ + d]);
        xv = bf2f(xc[(mb + t0) * DI_ + d]);
    }
    for (int t = t0; t < t1; ++t) {
        float dl_n = 0.f, xv_n = 0.f;
        if (t + 1 < t1) {
            dl_n = bf2f(din[(mb + t + 1) * DI_ + d]);
            xv_n = bf2f(xc[(mb + t + 1) * DI_ + d]);
        }
        const float* row = dbl + (mb + t) * 56;
        S += dl;
        float dlxv = dl * xv;
        const float4* pb = reinterpret_cast<const float4*>(row + 24);
#pragma unroll
        for (int j = 0; j < 4; ++j) {
            float4 B4 = pb[j];
            float e0 = __builtin_amdgcn_exp2f(dl * A[4 * j + 0]);
            float e1 = __builtin_amdgcn_exp2f(dl * A[4 * j + 1]);
            float e2 = __builtin_amdgcn_exp2f(dl * A[4 * j + 2]);
            float e3 = __builtin_amdgcn_exp2f(dl * A[4 * j + 3]);
            h[4 * j + 0] = e0 * h[4 * j + 0] + dlxv * B4.x;
            h[4 * j + 1] = e1 * h[4 * j + 1] + dlxv * B4.y;
            h[4 * j + 2] = e2 * h[4 * j + 2] + dlxv * B4.z;
            h[4 * j + 3] = e3 * h[4 * j + 3] + dlxv * B4.w;
        }
        dl = dl_n; xv = xv_n;
    }
    int bd = b * 12 + dblk;
    size_t base = ((size_t)dir * SGRIDT + (size_t)bd * SEGT + s) * 16 * 64 + lane;
#pragma unroll
    for (int n = 0; n < 16; ++n) {
        P_buf[base + (size_t)n * 64] = f2bf(__builtin_amdgcn_exp2f(A[n] * S));
        q_buf[base + (size_t)n * 64] = f2bf(h[n]);
    }
}

// Phase 2: grid (192, 4, 2): y = state quad, z = dir.
template<int SEGT>
__global__ __launch_bounds__(64) void scan_combine_kernel(
    const u16* __restrict__ P_buf, u16* __restrict__ q_buf)
{
    const int SGRIDT = NBD * SEGT;
    int lane = threadIdx.x;
    int bd = blockIdx.x;
    int nq = blockIdx.y;
    size_t dbase = (size_t)blockIdx.z * SGRIDT * 16 * 64;
    float h[4] = {0.f, 0.f, 0.f, 0.f};
    for (int s = 0; s < SEGT; ++s) {
        size_t base = dbase + ((size_t)(bd * SEGT + s) * 16 + nq * 4) * 64 + lane;
#pragma unroll
        for (int n = 0; n < 4; ++n) {
            size_t idx = base + (size_t)n * 64;
            float Pv = bf2f(P_buf[idx]);
            float qv = bf2f(q_buf[idx]);
            q_buf[idx] = f2bf(h[n]);
            h[n] = Pv * h[n] + qv;
        }
    }
}

// Phase 3: rescan from true hin; writes UNGATED y (gate applied in out_proj GEMM).
template<int SEGT>
__global__ __launch_bounds__(256) void scan_part3_kernel(
    const u16* __restrict__ xc2, const float* __restrict__ dbl2,
    const float* __restrict__ Alog_l, const float* __restrict__ Dp_l,
    const u16* __restrict__ q_buf,
    u16* __restrict__ y0, u16* __restrict__ y1, const u16* __restrict__ delta2)
{
    const int TLT = (L_ + SEGT - 1) / SEGT;
    const int SGRIDT = NBD * SEGT;
    int dir = blockIdx.y;
    const u16* xc = xc2 + (size_t)dir * M_ * DI_;
    const float* dbl = dbl2 + (size_t)dir * M_ * 56;
    const float* Alog = Alog_l + (size_t)dir * DI_ * DS_;
    const float* Dp = Dp_l + (size_t)dir * DI_;
    const u16* din = delta2 + (size_t)dir * M_ * DI_;
    u16* yb = dir ? y1 : y0;

    int tid = threadIdx.x;
    int wave = tid >> 6, lane = tid & 63;
    int s = blockIdx.x % SEGT;
    int bq = blockIdx.x / SEGT;
    int b = bq / 3, dq = bq % 3;
    int dblk = dq * 4 + wave;
    int d = dblk * 64 + lane;
    size_t mb = (size_t)b * L_;
    int t0 = s * TLT;
    int t1 = (t0 + TLT < L_) ? (t0 + TLT) : L_;

    float A[16];
    {
        const float4* ap = reinterpret_cast<const float4*>(Alog + (size_t)d * 16);
#pragma unroll
        for (int i = 0; i < 4; ++i) {
            float4 a4 = ap[i];
            A[4 * i + 0] = -LOG2E * __expf(a4.x); A[4 * i + 1] = -LOG2E * __expf(a4.y);
            A[4 * i + 2] = -LOG2E * __expf(a4.z); A[4 * i + 3] = -LOG2E * __expf(a4.w);
        }
    }
    float Dval = Dp[d];
    int bd = b * 12 + dblk;
    float h[16];
    {
        size_t base = ((size_t)dir * SGRIDT + (size_t)bd * SEGT + s) * 16 * 64 + lane;
#pragma unroll
        for (int n = 0; n < 16; ++n) h[n] = bf2f(q_buf[base + (size_t)n * 64]);
    }

    float dl = 0.f, xv = 0.f;
    if (t0 < t1) {
        dl = bf2f(din[(mb + t0) * DI_ + d]);
        xv = bf2f(xc[(mb + t0) * DI_ + d]);
    }
    for (int t = t0; t < t1; ++t) {
        float dl_n = 0.f, xv_n = 0.f;
        if (t + 1 < t1) {
            dl_n = bf2f(din[(mb + t + 1) * DI_ + d]);
            xv_n = bf2f(xc[(mb + t + 1) * DI_ + d]);
        }
        const float* row = dbl + (mb + t) * 56;
        float dlxv = dl * xv;
        const float4* pb = reinterpret_cast<const float4*>(row + 24);
        const float4* pc = reinterpret_cast<const float4*>(row + 40);
        float a0 = 0.f, a1 = 0.f, a2 = 0.f, a3 = 0.f;
#pragma unroll
        for (int j = 0; j < 4; ++j) {
            float4 B4 = pb[j], C4 = pc[j];
            float e0 = __builtin_amdgcn_exp2f(dl * A[4 * j + 0]);
            float e1 = __builtin_amdgcn_exp2f(dl * A[4 * j + 1]);
            float e2 = __builtin_amdgcn_exp2f(dl * A[4 * j + 2]);
            float e3 = __builtin_amdgcn_exp2f(dl * A[4 * j + 3]);
            h[4 * j + 0] = e0 * h[4 * j + 0] + dlxv * B4.x;
            h[4 * j + 1] = e1 * h[4 * j + 1] + dlxv * B4.y;
            h[4 * j + 2] = e2 * h[4 * j + 2] + dlxv * B4.z;
            h[4 * j + 3] = e3 * h[4 * j + 3] + dlxv * B4.w;
            a0 += h[4 * j + 0] * C4.x;
            a1 += h[4 * j + 1] * C4.y;
            a2 += h[4 * j + 2] * C4.z;
            a3 += h[4 * j + 3] * C4.w;
        }
        float y = (a0 + a1) + (a2 + a3) + xv * Dval;
        int lorig = dir ? (L_ - 1 - t) : t;
        yb[(mb + lorig) * DI_ + d] = f2bf(y);
        dl = dl_n; xv = xv_n;
    }
}

// final: residual+hidden, rmsnorm, permute+slice, store bf16 or f32 per flag
__global__ __launch_bounds__(128) void final_kernel(
    const float* __restrict__ hidden, const float* __restrict__ resid,
    const float* __restrict__ w, void* __restrict__ out,
    const int* __restrict__ bad)
{
    int blk = blockIdx.x;
    int b = blk / 446, tok = blk % 446;
    int lorig; size_t dst;
    if (tok == 0)      { lorig = 247; dst = (size_t)b * D_; }
    else if (tok <= 14){ int j = tok - 1; lorig = 49 + j; dst = 6144 + ((size_t)b * 14 + j) * D_; }
    else               { int v = tok - 15; lorig = (v < 184) ? (63 + v) : (64 + v);
                         dst = 92160 + ((size_t)b * 431 + v) * D_; }
    size_t base = ((size_t)b * L_ + lorig) * D_;
    int tid = threadIdx.x;
    float v3[3]; float ss = 0.f;
#pragma unroll
    for (int i = 0; i < 3; ++i) {
        int c = tid + i * 128;
        float r = hidden[base + c] + resid[base + c];
        v3[i] = r; ss += r * r;
    }
    ss += __shfl_xor(ss, 32); ss += __shfl_xor(ss, 16); ss += __shfl_xor(ss, 8);
    ss += __shfl_xor(ss, 4);  ss += __shfl_xor(ss, 2);  ss += __shfl_xor(ss, 1);
    __shared__ float sred[2];
    if ((tid & 63) == 0) sred[tid >> 6] = ss;
    __syncthreads();
    float scale = rsqrtf((sred[0] + sred[1]) * (1.f / D_) + 1e-5f);
    int isbf = (*bad == 0);
#pragma unroll
    for (int i = 0; i < 3; ++i) {
        int c = tid + i * 128;
        float val = v3[i] * scale * w[c];
        if (isbf) ((u16*)out)[dst + c] = f2bf(val);
        else      ((float*)out)[dst + c] = val;
    }
}

extern "C" void kernel_launch(void* const* d_in, const int* in_sizes, int n_in,
                              void* d_out, int out_size, void* d_ws, size_t ws_size,
                              hipStream_t stream) {
    char* wsb = (char*)d_ws;
    int* bad = (int*)wsb;  wsb += 16;

    const int cn[11] = {2359296, 24576, 6144, 344064, 147456, 6144, 98304,
                        6144, 1179648, 1536, 384};
    const int raw_idx[11] = {4, 5, 6, 7, 8, 9, 10, 11, 12, 13, 14};
    const int tobf[11]    = {1, 0, 0, 1, 0, 0, 0, 0, 1, 0, 0};
    void* canon[11];
    for (int i = 0; i < 11; ++i) {
        canon[i] = (void*)wsb;
        wsb += (size_t)cn[i] * (tobf[i] ? 2 : 4);
    }
    const u16*   inWb = (const u16*)canon[0];
    const float* cW   = (const float*)canon[1];
    const float* cB   = (const float*)canon[2];
    const u16*   xpWb = (const u16*)canon[3];
    const float* dtW  = (const float*)canon[4];
    const float* dtB  = (const float*)canon[5];
    const float* Alog = (const float*)canon[6];
    const float* Dsk  = (const float*)canon[7];
    const u16*   outWb= (const u16*)canon[8];
    const float* nw   = (const float*)canon[9];
    const float* fnw  = (const float*)canon[10];

    float* hidden = (float*)wsb;  wsb += (size_t)M_ * D_ * 4;
    float* resid  = (float*)wsb;  wsb += (size_t)M_ * D_ * 4;
    float* dbl2   = (float*)wsb;  wsb += (size_t)2 * M_ * 56 * 4;
    u16*   xz     = (u16*)wsb;    wsb += (size_t)M_ * 1536 * 2;
    u16*   xc2    = (u16*)wsb;    wsb += (size_t)2 * M_ * DI_ * 2;
    u16*   y0     = (u16*)wsb;    wsb += (size_t)M_ * DI_ * 2;       // hbf aliases
    u16*   delta2 = (u16*)wsb;    wsb += (size_t)2 * M_ * DI_ * 2;
    // P/q appended last; size depends on SEG choice (runtime, deterministic)
    size_t pq16 = (size_t)2 * (NBD * 16) * 16 * 64 * 2;   // 12.58 MB each
    size_t pq32 = (size_t)2 * (NBD * 32) * 16 * 64 * 2;   // 25.17 MB each
    size_t base_used = (size_t)(wsb - (char*)d_ws);
    int seg32 = (base_used + 2 * pq32) <= ws_size;
    size_t pqsz = seg32 ? pq32 : pq16;
    u16* P_buf = (u16*)wsb;       wsb += pqsz;
    u16* q_buf = (u16*)wsb;       wsb += pqsz;
    u16* hbf = y0;
    u16* y1  = P_buf;   // P dead after combine; part3 then writes y1 (12.16MB <= pqsz)

    hipMemsetAsync(bad, 0, 4, stream);
    detect_kernel<<<384, 256, 0, stream>>>((const u16*)d_in[10], bad);
    {
        CvtArgs ca;
        int maxn = 0;
        for (int i = 0; i < 11; ++i) {
            ca.src[i] = d_in[raw_idx[i]]; ca.dst[i] = canon[i];
            ca.n[i] = cn[i]; ca.tobf[i] = tobf[i];
            if (cn[i] > maxn) maxn = cn[i];
        }
        cvt_all_kernel<<<dim3((maxn + 255) / 256, 11), 256, 0, stream>>>(ca, bad);
    }

    build_hidden_kernel<<<(M_ * D_) / 256, 256, 0, stream>>>(
        d_in[0], d_in[2], d_in[3], hidden, bad);

    const int gmb = (M_ + 127) / 128;      // 62
    for (int l = 0; l < 4; ++l) {
        const float* dtWl = dtW + (size_t)l * 2 * DI_ * DTR_;
        const float* dtBl = dtB + (size_t)l * 2 * DI_;
        const float* All  = Alog + (size_t)l * 2 * DI_ * DS_;
        const float* Dl   = Dsk + (size_t)l * 2 * DI_;
        resnorm_kernel<<<M_, 128, 0, stream>>>(hidden, resid, nw + (size_t)l * D_, hbf, l == 0);
        gemm_mfma_bt<0, 0, 0><<<dim3(gmb, 1536 / 128), 256, 0, stream>>>(
            hbf, nullptr, nullptr, inWb + (size_t)l * 1536 * D_, xz, M_, 1536, D_, 1536, 1.f);
        conv_fused_kernel<<<B_ * CNCH, 384, 0, stream>>>(
            xz, cW + (size_t)l * 2 * DI_ * 4, cB + (size_t)l * 2 * DI_, xc2);
        xproj_gemm_kernel<<<dim3(gmb, 2), 256, 0, stream>>>(
            xc2, xpWb + (size_t)l * 2 * 56 * DI_, dbl2);
        dtproj_gemm_kernel<<<dim3(gmb, DI_ / 128, 2), 256, 0, stream>>>(
            dbl2, dtWl, dtBl, delta2);
        if (seg32) {
            scan_part1_kernel<32><<<dim3(B_ * 3 * 32, 2), 256, 0, stream>>>(
                xc2, dbl2, delta2, All, P_buf, q_buf);
            scan_combine_kernel<32><<<dim3(NBD, 4, 2), 64, 0, stream>>>(P_buf, q_buf);
            scan_part3_kernel<32><<<dim3(B_ * 3 * 32, 2), 256, 0, stream>>>(
                xc2, dbl2, All, Dl, q_buf, y0, y1, delta2);
        } else {
            scan_part1_kernel<16><<<dim3(B_ * 3 * 16, 2), 256, 0, stream>>>(
                xc2, dbl2, delta2, All, P_buf, q_buf);
            scan_combine_kernel<16><<<dim3(NBD, 4, 2), 64, 0, stream>>>(P_buf, q_buf);
            scan_part3_kernel<16><<<dim3(B_ * 3 * 16, 2), 256, 0, stream>>>(
                xc2, dbl2, All, Dl, q_buf, y0, y1, delta2);
        }
        gemm_mfma_bt<1, 1, 1><<<dim3(gmb, 384 / 128), 256, 0, stream>>>(
            y0, y1, xz, outWb + (size_t)l * D_ * DI_, hidden, M_, 384, DI_, 384, 0.5f);
    }

    final_kernel<<<B_ * 446, 128, 0, stream>>>(hidden, resid, fnw, d_out, bad);
}

// Round 15
// 977.674 us; speedup vs baseline: 1.1209x; 1.1209x over previous
//
#include <hip/hip_runtime.h>

typedef unsigned short u16;
typedef __attribute__((ext_vector_type(8))) short short8;
typedef __attribute__((ext_vector_type(4))) float float4v;

#define B_   16
#define L_   495
#define D_   384
#define DI_  768
#define DS_  16
#define DTR_ 24
#define SEG  16
#define TL   31   // ceil(495/16)
#define M_   (B_ * L_)
#define NBD  (B_ * 12)            // 192 (b,d-block) pairs
#define SGRID (NBD * SEG)         // 3072 flat scan units per dir
#define LOG2E 1.44269504f
#define CNCH 15
#define CTL  34

__device__ __forceinline__ float bf2f(u16 u) {
    return __uint_as_float(((unsigned)u) << 16);
}
__device__ __forceinline__ u16 f2bf(float f) {
    unsigned u = __float_as_uint(f);
    unsigned r = 0x7fffu + ((u >> 16) & 1u);
    return (u16)((u + r) >> 16);
}
__device__ __forceinline__ float silu_f(float x) {
    return x / (1.f + __expf(-x));
}

// ---- dtype detector (parallel): A_log in [0,2.78] as bf16 => bad==0 -> bf16.
__global__ __launch_bounds__(256) void detect_kernel(
    const u16* __restrict__ alog_raw, int* __restrict__ bad)
{
    int i = blockIdx.x * 256 + threadIdx.x;
    float v = bf2f(alog_raw[i]);
    int b = !(v >= -1e-3f && v <= 2.8f);
    unsigned long long m = __ballot(b);
    if ((threadIdx.x & 63) == 0 && m) atomicAdd(bad, (int)__popcll(m));
}

// ---- batched convert (blockIdx.y = tensor). tobf: emit bf16 instead of f32.
struct CvtArgs {
    const void* src[11];
    void* dst[11];
    int n[11];
    int tobf[11];
};
__global__ __launch_bounds__(256) void cvt_all_kernel(CvtArgs a, const int* __restrict__ bad)
{
    int t = blockIdx.y;
    int i = blockIdx.x * 256 + threadIdx.x;
    if (i >= a.n[t]) return;
    int isbf = (*bad == 0);
    if (a.tobf[t]) {
        u16 v = isbf ? ((const u16*)a.src[t])[i] : f2bf(((const float*)a.src[t])[i]);
        ((u16*)a.dst[t])[i] = v;
    } else {
        float v = isbf ? bf2f(((const u16*)a.src[t])[i]) : ((const float*)a.src[t])[i];
        ((float*)a.dst[t])[i] = v;
    }
}

// hidden[b,l,c] = concat(cjv[:247], cls, cjv[247:]) + pos_embed  (raw inputs)
__global__ __launch_bounds__(256) void build_hidden_kernel(
    const void* __restrict__ cjv, const void* __restrict__ cls,
    const void* __restrict__ pos, float* __restrict__ hidden,
    const int* __restrict__ bad)
{
    int isbf = (*bad == 0);
    int i = blockIdx.x * 256 + threadIdx.x;
    int c = i % D_;
    int l = (i / D_) % L_;
    int b = i / (D_ * L_);
    size_t si;
    const void* sp;
    if (l < 247)       { sp = cjv; si = ((size_t)b * 494 + l) * D_ + c; }
    else if (l == 247) { sp = cls; si = c; }
    else               { sp = cjv; si = ((size_t)b * 494 + (l - 1)) * D_ + c; }
    float v = isbf ? bf2f(((const u16*)sp)[si]) : ((const float*)sp)[si];
    size_t pi = (size_t)l * D_ + c;
    float p = isbf ? bf2f(((const u16*)pos)[pi]) : ((const float*)pos)[pi];
    hidden[i] = v + p;
}

// resid = hidden (+ resid); hbf <- bf16(rmsnorm(resid)*w)
__global__ __launch_bounds__(128) void resnorm_kernel(
    const float* __restrict__ hidden, float* __restrict__ resid,
    const float* __restrict__ w, u16* __restrict__ hbf, int first)
{
    int m = blockIdx.x, tid = threadIdx.x;
    size_t base = (size_t)m * D_;
    float v[3]; float ss = 0.f;
#pragma unroll
    for (int i = 0; i < 3; ++i) {
        int c = tid + i * 128;
        float r = hidden[base + c];
        if (!first) r += resid[base + c];
        resid[base + c] = r;
        v[i] = r; ss += r * r;
    }
    ss += __shfl_xor(ss, 32); ss += __shfl_xor(ss, 16); ss += __shfl_xor(ss, 8);
    ss += __shfl_xor(ss, 4);  ss += __shfl_xor(ss, 2);  ss += __shfl_xor(ss, 1);
    __shared__ float sred[2];
    if ((tid & 63) == 0) sred[tid >> 6] = ss;
    __syncthreads();
    float scale = rsqrtf((sred[0] + sred[1]) * (1.f / D_) + 1e-5f);
#pragma unroll
    for (int i = 0; i < 3; ++i) {
        int c = tid + i * 128;
        hbf[base + c] = f2bf(v[i] * scale * w[c]);
    }
}

// ===== MFMA GEMM (128x128): C = alpha * A(M,K)bf16 @ W(N,K)bf16^T =====
template<int CF32>
__global__ __launch_bounds__(256) void gemm_mfma_bt(
    const u16* __restrict__ A, const u16* __restrict__ W, void* __restrict__ Cv,
    int M, int N, int K, int ldc, float alpha)
{
    __shared__ __align__(16) u16 As[128 * 40];
    __shared__ __align__(16) u16 Ws[128 * 40];
    int tid = threadIdx.x;
    int wave = tid >> 6, lane = tid & 63;
    int m0 = blockIdx.x * 128, n0 = blockIdx.y * 128;
    int wm = (wave >> 1) * 64, wn = (wave & 1) * 64;
    int ml = lane & 15, quad = lane >> 4;

    float4v acc[4][4];
#pragma unroll
    for (int i = 0; i < 4; ++i)
#pragma unroll
        for (int j = 0; j < 4; ++j)
#pragma unroll
            for (int r = 0; r < 4; ++r) acc[i][j][r] = 0.f;

    int srow = tid >> 2;
    int scol = (tid & 3) * 8;

    for (int k0 = 0; k0 < K; k0 += 32) {
#pragma unroll
        for (int p = 0; p < 2; ++p) {
            int row = srow + p * 64;
            int gm = m0 + row; if (gm >= M) gm = M - 1;
            *(uint4*)&As[row * 40 + scol] =
                *(const uint4*)(A + (size_t)gm * K + k0 + scol);
            int gn = n0 + row;
            *(uint4*)&Ws[row * 40 + scol] =
                *(const uint4*)(W + (size_t)gn * K + k0 + scol);
        }
        __syncthreads();
        short8 af[4], bfr[4];
#pragma unroll
        for (int i = 0; i < 4; ++i) {
            af[i]  = *(const short8*)&As[(wm + i * 16 + ml) * 40 + quad * 8];
            bfr[i] = *(const short8*)&Ws[(wn + i * 16 + ml) * 40 + quad * 8];
        }
#pragma unroll
        for (int i = 0; i < 4; ++i)
#pragma unroll
            for (int j = 0; j < 4; ++j)
                acc[i][j] = __builtin_amdgcn_mfma_f32_16x16x32_bf16(
                    af[i], bfr[j], acc[i][j], 0, 0, 0);
        __syncthreads();
    }

#pragma unroll
    for (int i = 0; i < 4; ++i)
#pragma unroll
        for (int j = 0; j < 4; ++j)
#pragma unroll
            for (int r = 0; r < 4; ++r) {
                int m = m0 + wm + i * 16 + quad * 4 + r;
                if (m >= M) continue;
                int n = n0 + wn + j * 16 + ml;
                float val = alpha * acc[i][j][r];
                if (CF32) ((float*)Cv)[(size_t)m * ldc + n] = val;
                else      ((u16*)Cv)[(size_t)m * ldc + n] = f2bf(val);
            }
}

// ===== out_proj GEMM (64x64 tiles, 744 blocks): hidden = 0.5*(y0+y1) @ outW^T
__global__ __launch_bounds__(256) void gemm_out_kernel(
    const u16* __restrict__ y0, const u16* __restrict__ y1,
    const u16* __restrict__ W, float* __restrict__ C)
{
    __shared__ __align__(16) u16 As[64 * 40];
    __shared__ __align__(16) u16 Ws[64 * 40];
    int tid = threadIdx.x;
    int wave = tid >> 6, lane = tid & 63;
    int m0 = blockIdx.x * 64, n0 = blockIdx.y * 64;
    int wm = wave * 16;
    int ml = lane & 15, quad = lane >> 4;

    float4v acc[4];
#pragma unroll
    for (int j = 0; j < 4; ++j)
#pragma unroll
        for (int r = 0; r < 4; ++r) acc[j][r] = 0.f;

    int srow = tid >> 2;          // 0..63
    int scol = (tid & 3) * 8;     // 0,8,16,24

    for (int k0 = 0; k0 < DI_; k0 += 32) {
        {
            int gm = m0 + srow; if (gm >= M_) gm = M_ - 1;
            short8 a0 = *(const short8*)(y0 + (size_t)gm * DI_ + k0 + scol);
            short8 a1 = *(const short8*)(y1 + (size_t)gm * DI_ + k0 + scol);
            u16 tmp[8];
#pragma unroll
            for (int r = 0; r < 8; ++r)
                tmp[r] = f2bf(bf2f((u16)a0[r]) + bf2f((u16)a1[r]));
            *(uint4*)&As[srow * 40 + scol] = *(const uint4*)tmp;
            *(uint4*)&Ws[srow * 40 + scol] =
                *(const uint4*)(W + (size_t)(n0 + srow) * DI_ + k0 + scol);
        }
        __syncthreads();
        short8 af = *(const short8*)&As[(wm + ml) * 40 + quad * 8];
        short8 bfr[4];
#pragma unroll
        for (int j = 0; j < 4; ++j)
            bfr[j] = *(const short8*)&Ws[(j * 16 + ml) * 40 + quad * 8];
#pragma unroll
        for (int j = 0; j < 4; ++j)
            acc[j] = __builtin_amdgcn_mfma_f32_16x16x32_bf16(af, bfr[j], acc[j], 0, 0, 0);
        __syncthreads();
    }

#pragma unroll
    for (int j = 0; j < 4; ++j)
#pragma unroll
        for (int r = 0; r < 4; ++r) {
            int m = m0 + wm + quad * 4 + r;
            if (m >= M_) continue;
            int n = n0 + j * 16 + ml;
            C[(size_t)m * D_ + n] = 0.5f * acc[j][r];
        }
}

// ===== xproj MFMA GEMM: dbl2[dir](m,56) = xc2[dir](M,768) @ xpWb[dir](56,768)^T
__global__ __launch_bounds__(256) void xproj_gemm_kernel(
    const u16* __restrict__ xc2, const u16* __restrict__ xpWb_l,
    float* __restrict__ dbl2)
{
    int dir = blockIdx.y;
    const u16* A = xc2 + (size_t)dir * M_ * DI_;
    const u16* W = xpWb_l + (size_t)dir * 56 * DI_;
    float* C = dbl2 + (size_t)dir * M_ * 56;

    __shared__ __align__(16) u16 As[128 * 40];
    __shared__ __align__(16) u16 Ws[64 * 40];
    int tid = threadIdx.x;
    int wave = tid >> 6, lane = tid & 63;
    int m0 = blockIdx.x * 128;
    int wm = wave * 32;
    int ml = lane & 15, quad = lane >> 4;

    float4v acc[2][4];
#pragma unroll
    for (int i = 0; i < 2; ++i)
#pragma unroll
        for (int j = 0; j < 4; ++j)
#pragma unroll
            for (int r = 0; r < 4; ++r) acc[i][j][r] = 0.f;

    int srow = tid >> 2;
    int scol = (tid & 3) * 8;

    for (int k0 = 0; k0 < DI_; k0 += 32) {
#pragma unroll
        for (int p = 0; p < 2; ++p) {
            int row = srow + p * 64;
            int gm = m0 + row; if (gm >= M_) gm = M_ - 1;
            *(uint4*)&As[row * 40 + scol] =
                *(const uint4*)(A + (size_t)gm * DI_ + k0 + scol);
        }
        *(uint4*)&Ws[srow * 40 + scol] =
            *(const uint4*)(W + (size_t)srow * DI_ + k0 + scol);
        __syncthreads();
        short8 af[2], bfr[4];
#pragma unroll
        for (int i = 0; i < 2; ++i)
            af[i] = *(const short8*)&As[(wm + i * 16 + ml) * 40 + quad * 8];
#pragma unroll
        for (int j = 0; j < 4; ++j)
            bfr[j] = *(const short8*)&Ws[(j * 16 + ml) * 40 + quad * 8];
#pragma unroll
        for (int i = 0; i < 2; ++i)
#pragma unroll
            for (int j = 0; j < 4; ++j)
                acc[i][j] = __builtin_amdgcn_mfma_f32_16x16x32_bf16(
                    af[i], bfr[j], acc[i][j], 0, 0, 0);
        __syncthreads();
    }

#pragma unroll
    for (int i = 0; i < 2; ++i)
#pragma unroll
        for (int j = 0; j < 4; ++j)
#pragma unroll
            for (int r = 0; r < 4; ++r) {
                int m = m0 + wm + i * 16 + quad * 4 + r;
                int n = j * 16 + ml;
                if (m < M_ && n < 56)
                    C[(size_t)m * 56 + n] = acc[i][j][r];
            }
}

// ===== dtproj MFMA GEMM: delta2[dir](M,768) = softplus(dt(M,24)@dtW(768,24)^T + dtb)
__global__ __launch_bounds__(256) void dtproj_gemm_kernel(
    const float* __restrict__ dbl2, const float* __restrict__ dtW_l,
    const float* __restrict__ dtb_l, u16* __restrict__ delta2)
{
    int dir = blockIdx.z;
    const float* dbl = dbl2 + (size_t)dir * M_ * 56;
    const float* dtW = dtW_l + (size_t)dir * DI_ * DTR_;
    const float* dtb = dtb_l + (size_t)dir * DI_;
    u16* dout = delta2 + (size_t)dir * M_ * DI_;

    __shared__ __align__(16) u16 As[128 * 40];
    __shared__ __align__(16) u16 Ws[128 * 40];
    int tid = threadIdx.x;
    int wave = tid >> 6, lane = tid & 63;
    int m0 = blockIdx.x * 128, n0 = blockIdx.y * 128;
    int wm = (wave >> 1) * 64, wn = (wave & 1) * 64;
    int ml = lane & 15, quad = lane >> 4;

    {
        int r = tid >> 1, hh = tid & 1;
        int gm = m0 + r; if (gm >= M_) gm = M_ - 1;
        const float* srcA = dbl + (size_t)gm * 56 + hh * 12;
        const float* srcW = dtW + (size_t)(n0 + r) * DTR_ + hh * 12;
#pragma unroll
        for (int i = 0; i < 6; ++i) {
            unsigned a = (unsigned)f2bf(srcA[2 * i]) | ((unsigned)f2bf(srcA[2 * i + 1]) << 16);
            unsigned w = (unsigned)f2bf(srcW[2 * i]) | ((unsigned)f2bf(srcW[2 * i + 1]) << 16);
            *(unsigned*)&As[r * 40 + hh * 12 + 2 * i] = a;
            *(unsigned*)&Ws[r * 40 + hh * 12 + 2 * i] = w;
        }
        if (hh) {
            *(uint4*)&As[r * 40 + 24] = make_uint4(0, 0, 0, 0);
            *(uint4*)&Ws[r * 40 + 24] = make_uint4(0, 0, 0, 0);
        }
    }
    __syncthreads();

    float4v acc[4][4];
#pragma unroll
    for (int i = 0; i < 4; ++i)
#pragma unroll
        for (int j = 0; j < 4; ++j)
#pragma unroll
            for (int r = 0; r < 4; ++r) acc[i][j][r] = 0.f;

    short8 af[4], bfr[4];
#pragma unroll
    for (int i = 0; i < 4; ++i) {
        af[i]  = *(const short8*)&As[(wm + i * 16 + ml) * 40 + quad * 8];
        bfr[i] = *(const short8*)&Ws[(wn + i * 16 + ml) * 40 + quad * 8];
    }
#pragma unroll
    for (int i = 0; i < 4; ++i)
#pragma unroll
        for (int j = 0; j < 4; ++j)
            acc[i][j] = __builtin_amdgcn_mfma_f32_16x16x32_bf16(
                af[i], bfr[j], acc[i][j], 0, 0, 0);

#pragma unroll
    for (int i = 0; i < 4; ++i)
#pragma unroll
        for (int j = 0; j < 4; ++j) {
            int n = n0 + wn + j * 16 + ml;
            float bv = dtb[n];
#pragma unroll
            for (int r = 0; r < 4; ++r) {
                int m = m0 + wm + i * 16 + quad * 4 + r;
                if (m >= M_) continue;
                float s = acc[i][j][r] + bv;
                float dl = (s > 20.f) ? s : __logf(1.f + __expf(s));
                dout[(size_t)m * DI_ + n] = f2bf(dl);
            }
        }
}

// ===== fused dual-direction causal depthwise conv (K=4) + bias + silu =====
__global__ __launch_bounds__(384) void conv_fused_kernel(
    const u16* __restrict__ xz, const float* __restrict__ cw_l,
    const float* __restrict__ cb_l, u16* __restrict__ xc2)
{
    int dp = threadIdx.x;
    int d = dp * 2;
    int blk = blockIdx.x;
    int b = blk / CNCH, c = blk % CNCH;
    int t0 = c * CTL;
    int t1 = t0 + CTL; if (t1 > L_ + 3) t1 = L_ + 3;
    size_t mb = (size_t)b * L_;
    u16* xc0 = xc2;
    u16* xc1 = xc2 + (size_t)M_ * DI_;

    float w0[2][4], w1[2][4];
    {
        float4 a = *(const float4*)&cw_l[d * 4];
        float4 bq = *(const float4*)&cw_l[d * 4 + 4];
        w0[0][0] = a.x; w0[0][1] = a.y; w0[0][2] = a.z; w0[0][3] = a.w;
        w0[1][0] = bq.x; w0[1][1] = bq.y; w0[1][2] = bq.z; w0[1][3] = bq.w;
        float4 e = *(const float4*)&cw_l[DI_ * 4 + d * 4];
        float4 f = *(const float4*)&cw_l[DI_ * 4 + d * 4 + 4];
        w1[0][0] = e.x; w1[0][1] = e.y; w1[0][2] = e.z; w1[0][3] = e.w;
        w1[1][0] = f.x; w1[1][1] = f.y; w1[1][2] = f.z; w1[1][3] = f.w;
    }
    float b00 = cb_l[d], b01 = cb_l[d + 1];
    float b10 = cb_l[DI_ + d], b11 = cb_l[DI_ + d + 1];

    unsigned win[4];
#pragma unroll
    for (int m = 0; m < 3; ++m) {
        int r = t0 - 3 + m;
        win[m] = (r >= 0 && r < L_) ?
            *(const unsigned*)&xz[(mb + r) * 1536 + d] : 0u;
    }

    for (int t = t0; t < t1; ++t) {
        win[3] = (t < L_) ? *(const unsigned*)&xz[(mb + t) * 1536 + d] : 0u;
        float x0[4], x1[4];
#pragma unroll
        for (int m = 0; m < 4; ++m) {
            x0[m] = __uint_as_float(win[m] << 16);
            x1[m] = __uint_as_float(win[m] & 0xffff0000u);
        }
        if (t < L_) {
            float a0 = b00 + w0[0][0] * x0[0] + w0[0][1] * x0[1]
                           + w0[0][2] * x0[2] + w0[0][3] * x0[3];
            float a1 = b01 + w0[1][0] * x1[0] + w0[1][1] * x1[1]
                           + w0[1][2] * x1[2] + w0[1][3] * x1[3];
            unsigned o = (unsigned)f2bf(silu_f(a0)) | ((unsigned)f2bf(silu_f(a1)) << 16);
            *(unsigned*)&xc0[(mb + t) * DI_ + d] = o;
        }
        if (t >= 3) {
            int s1 = L_ + 2 - t;
            float a0 = b10 + w1[0][3] * x0[0] + w1[0][2] * x0[1]
                           + w1[0][1] * x0[2] + w1[0][0] * x0[3];
            float a1 = b11 + w1[1][3] * x1[0] + w1[1][2] * x1[1]
                           + w1[1][1] * x1[2] + w1[1][0] * x1[3];
            unsigned o = (unsigned)f2bf(silu_f(a0)) | ((unsigned)f2bf(silu_f(a1)) << 16);
            *(unsigned*)&xc1[(mb + s1) * DI_ + d] = o;
        }
        win[0] = win[1]; win[1] = win[2]; win[2] = win[3];
    }
}

// ================= segmented selective scan (both dirs per launch) ==========
// Part 1: local scan; delta precomputed; P algebraic via sum(dl).
__global__ __launch_bounds__(256) void scan_part1_kernel(
    const u16* __restrict__ xc2, const float* __restrict__ dbl2,
    const u16* __restrict__ delta2, const float* __restrict__ Alog_l,
    u16* __restrict__ P_buf, u16* __restrict__ q_buf)
{
    int dir = blockIdx.y;
    const u16* xc = xc2 + (size_t)dir * M_ * DI_;
    const float* dbl = dbl2 + (size_t)dir * M_ * 56;
    const u16* din = delta2 + (size_t)dir * M_ * DI_;
    const float* Alog = Alog_l + (size_t)dir * DI_ * DS_;

    int tid = threadIdx.x;
    int wave = tid >> 6, lane = tid & 63;
    int s = blockIdx.x % SEG;
    int bq = blockIdx.x / SEG;
    int b = bq / 3, dq = bq % 3;
    int dblk = dq * 4 + wave;
    int d = dblk * 64 + lane;
    size_t mb = (size_t)b * L_;
    int t0 = s * TL;
    int t1 = (t0 + TL < L_) ? (t0 + TL) : L_;

    float A[16];
    {
        const float4* ap = reinterpret_cast<const float4*>(Alog + (size_t)d * 16);
#pragma unroll
        for (int i = 0; i < 4; ++i) {
            float4 a4 = ap[i];
            A[4 * i + 0] = -LOG2E * __expf(a4.x); A[4 * i + 1] = -LOG2E * __expf(a4.y);
            A[4 * i + 2] = -LOG2E * __expf(a4.z); A[4 * i + 3] = -LOG2E * __expf(a4.w);
        }
    }
    float h[16];
    float S = 0.f;
#pragma unroll
    for (int i = 0; i < 16; ++i) h[i] = 0.f;

    for (int t = t0; t < t1; ++t) {
        const float* row = dbl + (mb + t) * 56;
        float dl = bf2f(din[(mb + t) * DI_ + d]);
        S += dl;
        float xv = bf2f(xc[(mb + t) * DI_ + d]);
        float dlxv = dl * xv;
        const float4* pb = reinterpret_cast<const float4*>(row + 24);
#pragma unroll
        for (int j = 0; j < 4; ++j) {
            float4 B4 = pb[j];
            float e0 = __builtin_amdgcn_exp2f(dl * A[4 * j + 0]);
            float e1 = __builtin_amdgcn_exp2f(dl * A[4 * j + 1]);
            float e2 = __builtin_amdgcn_exp2f(dl * A[4 * j + 2]);
            float e3 = __builtin_amdgcn_exp2f(dl * A[4 * j + 3]);
            h[4 * j + 0] = e0 * h[4 * j + 0] + dlxv * B4.x;
            h[4 * j + 1] = e1 * h[4 * j + 1] + dlxv * B4.y;
            h[4 * j + 2] = e2 * h[4 * j + 2] + dlxv * B4.z;
            h[4 * j + 3] = e3 * h[4 * j + 3] + dlxv * B4.w;
        }
    }
    int bd = b * 12 + dblk;
    size_t base = ((size_t)dir * SGRID + (size_t)bd * SEG + s) * 16 * 64 + lane;
#pragma unroll
    for (int n = 0; n < 16; ++n) {
        P_buf[base + (size_t)n * 64] = f2bf(__builtin_amdgcn_exp2f(A[n] * S));
        q_buf[base + (size_t)n * 64] = f2bf(h[n]);
    }
}

// Phase 2: grid (192, 4, 2): y = state quad, z = dir.
__global__ __launch_bounds__(64) void scan_combine_kernel(
    const u16* __restrict__ P_buf, u16* __restrict__ q_buf)
{
    int lane = threadIdx.x;
    int bd = blockIdx.x;
    int nq = blockIdx.y;
    size_t dbase = (size_t)blockIdx.z * SGRID * 16 * 64;
    float h[4] = {0.f, 0.f, 0.f, 0.f};
    for (int s = 0; s < SEG; ++s) {
        size_t base = dbase + ((size_t)(bd * SEG + s) * 16 + nq * 4) * 64 + lane;
#pragma unroll
        for (int n = 0; n < 4; ++n) {
            size_t idx = base + (size_t)n * 64;
            float Pv = bf2f(P_buf[idx]);
            float qv = bf2f(q_buf[idx]);
            q_buf[idx] = f2bf(h[n]);
            h[n] = Pv * h[n] + qv;
        }
    }
}

// Phase 3: rescan from true hin; gated y to per-dir buffers.
__global__ __launch_bounds__(256) void scan_part3_kernel(
    const u16* __restrict__ xc2, const float* __restrict__ dbl2,
    const u16* __restrict__ xz, const float* __restrict__ Alog_l,
    const float* __restrict__ Dp_l, const u16* __restrict__ q_buf,
    u16* __restrict__ y0, u16* __restrict__ y1, const u16* __restrict__ delta2)
{
    int dir = blockIdx.y;
    const u16* xc = xc2 + (size_t)dir * M_ * DI_;
    const float* dbl = dbl2 + (size_t)dir * M_ * 56;
    const float* Alog = Alog_l + (size_t)dir * DI_ * DS_;
    const float* Dp = Dp_l + (size_t)dir * DI_;
    const u16* din = delta2 + (size_t)dir * M_ * DI_;
    u16* yb = dir ? y1 : y0;

    int tid = threadIdx.x;
    int wave = tid >> 6, lane = tid & 63;
    int s = blockIdx.x % SEG;
    int bq = blockIdx.x / SEG;
    int b = bq / 3, dq = bq % 3;
    int dblk = dq * 4 + wave;
    int d = dblk * 64 + lane;
    size_t mb = (size_t)b * L_;
    int t0 = s * TL;
    int t1 = (t0 + TL < L_) ? (t0 + TL) : L_;

    float A[16];
    {
        const float4* ap = reinterpret_cast<const float4*>(Alog + (size_t)d * 16);
#pragma unroll
        for (int i = 0; i < 4; ++i) {
            float4 a4 = ap[i];
            A[4 * i + 0] = -LOG2E * __expf(a4.x); A[4 * i + 1] = -LOG2E * __expf(a4.y);
            A[4 * i + 2] = -LOG2E * __expf(a4.z); A[4 * i + 3] = -LOG2E * __expf(a4.w);
        }
    }
    float Dval = Dp[d];
    int bd = b * 12 + dblk;
    float h[16];
    {
        size_t base = ((size_t)dir * SGRID + (size_t)bd * SEG + s) * 16 * 64 + lane;
#pragma unroll
        for (int n = 0; n < 16; ++n) h[n] = bf2f(q_buf[base + (size_t)n * 64]);
    }

    for (int t = t0; t < t1; ++t) {
        const float* row = dbl + (mb + t) * 56;
        float dl = bf2f(din[(mb + t) * DI_ + d]);
        float xv = bf2f(xc[(mb + t) * DI_ + d]);
        float dlxv = dl * xv;
        const float4* pb = reinterpret_cast<const float4*>(row + 24);
        const float4* pc = reinterpret_cast<const float4*>(row + 40);
        float a0 = 0.f, a1 = 0.f, a2 = 0.f, a3 = 0.f;
#pragma unroll
        for (int j = 0; j < 4; ++j) {
            float4 B4 = pb[j], C4 = pc[j];
            float e0 = __builtin_amdgcn_exp2f(dl * A[4 * j + 0]);
            float e1 = __builtin_amdgcn_exp2f(dl * A[4 * j + 1]);
            float e2 = __builtin_amdgcn_exp2f(dl * A[4 * j + 2]);
            float e3 = __builtin_amdgcn_exp2f(dl * A[4 * j + 3]);
            h[4 * j + 0] = e0 * h[4 * j + 0] + dlxv * B4.x;
            h[4 * j + 1] = e1 * h[4 * j + 1] + dlxv * B4.y;
            h[4 * j + 2] = e2 * h[4 * j + 2] + dlxv * B4.z;
            h[4 * j + 3] = e3 * h[4 * j + 3] + dlxv * B4.w;
            a0 += h[4 * j + 0] * C4.x;
            a1 += h[4 * j + 1] * C4.y;
            a2 += h[4 * j + 2] * C4.z;
            a3 += h[4 * j + 3] * C4.w;
        }
        float y = (a0 + a1) + (a2 + a3) + xv * Dval;
        int lorig = dir ? (L_ - 1 - t) : t;
        y *= silu_f(bf2f(xz[(mb + lorig) * 1536 + 768 + d]));
        yb[(mb + lorig) * DI_ + d] = f2bf(y);
    }
}

// final: residual+hidden, rmsnorm, permute+slice, store bf16 or f32 per flag
__global__ __launch_bounds__(128) void final_kernel(
    const float* __restrict__ hidden, const float* __restrict__ resid,
    const float* __restrict__ w, void* __restrict__ out,
    const int* __restrict__ bad)
{
    int blk = blockIdx.x;
    int b = blk / 446, tok = blk % 446;
    int lorig; size_t dst;
    if (tok == 0)      { lorig = 247; dst = (size_t)b * D_; }
    else if (tok <= 14){ int j = tok - 1; lorig = 49 + j; dst = 6144 + ((size_t)b * 14 + j) * D_; }
    else               { int v = tok - 15; lorig = (v < 184) ? (63 + v) : (64 + v);
                         dst = 92160 + ((size_t)b * 431 + v) * D_; }
    size_t base = ((size_t)b * L_ + lorig) * D_;
    int tid = threadIdx.x;
    float v3[3]; float ss = 0.f;
#pragma unroll
    for (int i = 0; i < 3; ++i) {
        int c = tid + i * 128;
        float r = hidden[base + c] + resid[base + c];
        v3[i] = r; ss += r * r;
    }
    ss += __shfl_xor(ss, 32); ss += __shfl_xor(ss, 16); ss += __shfl_xor(ss, 8);
    ss += __shfl_xor(ss, 4);  ss += __shfl_xor(ss, 2);  ss += __shfl_xor(ss, 1);
    __shared__ float sred[2];
    if ((tid & 63) == 0) sred[tid >> 6] = ss;
    __syncthreads();
    float scale = rsqrtf((sred[0] + sred[1]) * (1.f / D_) + 1e-5f);
    int isbf = (*bad == 0);
#pragma unroll
    for (int i = 0; i < 3; ++i) {
        int c = tid + i * 128;
        float val = v3[i] * scale * w[c];
        if (isbf) ((u16*)out)[dst + c] = f2bf(val);
        else      ((float*)out)[dst + c] = val;
    }
}

extern "C" void kernel_launch(void* const* d_in, const int* in_sizes, int n_in,
                              void* d_out, int out_size, void* d_ws, size_t ws_size,
                              hipStream_t stream) {
    char* wsb = (char*)d_ws;
    int* bad = (int*)wsb;  wsb += 16;

    const int cn[11] = {2359296, 24576, 6144, 344064, 147456, 6144, 98304,
                        6144, 1179648, 1536, 384};
    const int raw_idx[11] = {4, 5, 6, 7, 8, 9, 10, 11, 12, 13, 14};
    const int tobf[11]    = {1, 0, 0, 1, 0, 0, 0, 0, 1, 0, 0};
    void* canon[11];
    for (int i = 0; i < 11; ++i) {
        canon[i] = (void*)wsb;
        wsb += (size_t)cn[i] * (tobf[i] ? 2 : 4);
    }
    const u16*   inWb = (const u16*)canon[0];
    const float* cW   = (const float*)canon[1];
    const float* cB   = (const float*)canon[2];
    const u16*   xpWb = (const u16*)canon[3];
    const float* dtW  = (const float*)canon[4];
    const float* dtB  = (const float*)canon[5];
    const float* Alog = (const float*)canon[6];
    const float* Dsk  = (const float*)canon[7];
    const u16*   outWb= (const u16*)canon[8];
    const float* nw   = (const float*)canon[9];
    const float* fnw  = (const float*)canon[10];

    float* hidden = (float*)wsb;  wsb += (size_t)M_ * D_ * 4;
    float* resid  = (float*)wsb;  wsb += (size_t)M_ * D_ * 4;
    float* dbl2   = (float*)wsb;  wsb += (size_t)2 * M_ * 56 * 4;
    u16*   xz     = (u16*)wsb;    wsb += (size_t)M_ * 1536 * 2;
    u16*   xc2    = (u16*)wsb;    wsb += (size_t)2 * M_ * DI_ * 2;
    u16*   y0     = (u16*)wsb;    wsb += (size_t)M_ * DI_ * 2;           // hbf aliases
    u16*   P_buf  = (u16*)wsb;    wsb += (size_t)2 * SGRID * 16 * 64 * 2; // y1 aliases
    u16*   q_buf  = (u16*)wsb;    wsb += (size_t)2 * SGRID * 16 * 64 * 2;
    u16*   delta2 = (u16*)wsb;    wsb += (size_t)2 * M_ * DI_ * 2;       // ws >=147MB proven
    u16* hbf = y0;
    u16* y1  = P_buf;   // P dead after combine; part3 then writes y1

    hipMemsetAsync(bad, 0, 4, stream);
    detect_kernel<<<384, 256, 0, stream>>>((const u16*)d_in[10], bad);
    {
        CvtArgs ca;
        int maxn = 0;
        for (int i = 0; i < 11; ++i) {
            ca.src[i] = d_in[raw_idx[i]]; ca.dst[i] = canon[i];
            ca.n[i] = cn[i]; ca.tobf[i] = tobf[i];
            if (cn[i] > maxn) maxn = cn[i];
        }
        cvt_all_kernel<<<dim3((maxn + 255) / 256, 11), 256, 0, stream>>>(ca, bad);
    }

    build_hidden_kernel<<<(M_ * D_) / 256, 256, 0, stream>>>(
        d_in[0], d_in[2], d_in[3], hidden, bad);

    const int gmb = (M_ + 127) / 128;      // 62
    const int gmb64 = (M_ + 63) / 64;      // 124
    for (int l = 0; l < 4; ++l) {
        const float* dtWl = dtW + (size_t)l * 2 * DI_ * DTR_;
        const float* dtBl = dtB + (size_t)l * 2 * DI_;
        const float* All  = Alog + (size_t)l * 2 * DI_ * DS_;
        const float* Dl   = Dsk + (size_t)l * 2 * DI_;
        resnorm_kernel<<<M_, 128, 0, stream>>>(hidden, resid, nw + (size_t)l * D_, hbf, l == 0);
        gemm_mfma_bt<0><<<dim3(gmb, 1536 / 128), 256, 0, stream>>>(
            hbf, inWb + (size_t)l * 1536 * D_, xz, M_, 1536, D_, 1536, 1.f);
        conv_fused_kernel<<<B_ * CNCH, 384, 0, stream>>>(
            xz, cW + (size_t)l * 2 * DI_ * 4, cB + (size_t)l * 2 * DI_, xc2);
        xproj_gemm_kernel<<<dim3(gmb, 2), 256, 0, stream>>>(
            xc2, xpWb + (size_t)l * 2 * 56 * DI_, dbl2);
        dtproj_gemm_kernel<<<dim3(gmb, DI_ / 128, 2), 256, 0, stream>>>(
            dbl2, dtWl, dtBl, delta2);
        scan_part1_kernel<<<dim3(B_ * 3 * SEG, 2), 256, 0, stream>>>(
            xc2, dbl2, delta2, All, P_buf, q_buf);
        scan_combine_kernel<<<dim3(NBD, 4, 2), 64, 0, stream>>>(P_buf, q_buf);
        scan_part3_kernel<<<dim3(B_ * 3 * SEG, 2), 256, 0, stream>>>(
            xc2, dbl2, xz, All, Dl, q_buf, y0, y1, delta2);
        gemm_out_kernel<<<dim3(gmb64, D_ / 64), 256, 0, stream>>>(
            y0, y1, outWb + (size_t)l * D_ * DI_, hidden);
    }

    final_kernel<<<B_ * 446, 128, 0, stream>>>(hidden, resid, fnw, d_out, bad);
}